// Round 3
// baseline (860.376 us; speedup 1.0000x reference)
//
#include <hip/hip_runtime.h>
#include <hip/hip_fp16.h>

typedef _Float16 half8 __attribute__((ext_vector_type(8)));
typedef _Float16 half4 __attribute__((ext_vector_type(4)));
typedef float floatx4 __attribute__((ext_vector_type(4)));
typedef float fvec4 __attribute__((ext_vector_type(4)));

#define SS 50
#define HH 256
#define APAD 264                 // LDS row stride in halfs (528 B)
#define CABUF (16 * APAD)        // 4224 halfs per staging buffer
#define WHALF (768 * 256)        // halfs per weight matrix

__device__ __forceinline__ float sigm(float x) { return 1.f / (1.f + __expf(-x)); }
__device__ __forceinline__ float tanh_f(float x) {
    float ap = fabsf(x);
    float e2 = __expf(-2.f * ap);
    float th = (1.f - e2) / (1.f + e2);
    return (x < 0.f) ? -th : th;
}

// ---- phase 0: convert W_ih / W_hh fp32 -> fp16 into workspace ----
__global__ void cvt_w(const float* __restrict__ wih,
                      const float* __restrict__ whh,
                      _Float16* __restrict__ ws) {
    int idx = (blockIdx.x * 256 + threadIdx.x) * 4;
    const float* src = (idx < WHALF) ? (wih + idx) : (whh + (idx - WHALF));
    fvec4 v = *(const fvec4*)src;
    half4 h;
    h[0] = (_Float16)v.x; h[1] = (_Float16)v.y;
    h[2] = (_Float16)v.z; h[3] = (_Float16)v.w;
    *(half4*)(ws + idx) = h;
}

// ---- persistent fused kernel ----
// Dynamic LDS layout (halfs):
//   giL : Sc * 12288          (gi staging, thread-matched: tid*24)
//   cA  : 2 * CABUF           (C staging double buffer)
//   hA  : 2 * CABUF           (h f16 round-trip double buffer)
//   gL  : 16*SS floats        (G staged once per block, layout [s][row])
extern __shared__ _Float16 smem[];

// Weight residency strategy: the 48 half8 fragments (192 regs) are pinned
// into AGPRs ("a" constraint). gfx950 MFMA reads B directly from AGPR, and
// the unified RF lets accum_offset drop so arch VGPRs (~64-112) hold only
// accumulators/addresses/A-fragments. Previous "+v" pins forced 192 regs
// into the 128-reg arch half -> guaranteed scratch spill (WRITE_SIZE 165MB).
__global__ __launch_bounds__(512)
__attribute__((amdgpu_waves_per_eu(2, 2)))
void gru_all(
    const float* __restrict__ C, const float* __restrict__ G,
    const float* __restrict__ bih, const float* __restrict__ bhh,
    const _Float16* __restrict__ Wf, float* __restrict__ out, int Sc)
{
    _Float16* giL = smem;
    _Float16* cA  = smem + (size_t)Sc * 12288;
    _Float16* hAb = cA + 2 * CABUF;
    float*    gL  = (float*)(hAb + 2 * CABUF);

    const int tid  = threadIdx.x;
    const int w    = tid >> 6;
    const int lane = tid & 63;
    const int q    = lane >> 4;
    const int c    = lane & 15;
    const int rb   = blockIdx.x * 16;

    const _Float16* Wih = Wf;
    const _Float16* Whh = Wf + WHALF;

    // biases: bi (+ bh for r,z gates) folded into gi at store time; bh_n separate
    float bsum[6], bhn[2];
#pragma unroll
    for (int t2 = 0; t2 < 6; ++t2) {
        int g = t2 >> 1, t = t2 & 1;
        int n = g * 256 + w * 32 + t * 16 + c;
        bsum[t2] = bih[n] + (g < 2 ? bhh[n] : 0.f);
    }
#pragma unroll
    for (int t = 0; t < 2; ++t) bhn[t] = bhh[512 + w * 32 + t * 16 + c];

    float hreg[2][4];
#pragma unroll
    for (int t = 0; t < 2; ++t)
#pragma unroll
        for (int r = 0; r < 4; ++r) hreg[t][r] = 0.f;

    // init: zero h buffer 0, stage all G for this block's 16 rows
    for (int i = tid; i < CABUF; i += 512) hAb[i] = (_Float16)0.f;
    for (int i = tid; i < 16 * SS; i += 512)
        gL[i] = G[(size_t)(rb + (i & 15)) * SS + (i >> 4)];

    const int m_st = tid & 15;
    const int chk  = tid >> 4;             // 0..31, 8 floats each
    const float* crow = C + (size_t)(rb + m_st) * (SS * HH) + chk * 8;

    half8 wf[6][8];                        // 192 regs of weight fragments -> AGPRs
    int hp = 0;
    const int nch = (SS + Sc - 1) / Sc;

    for (int cc = 0; cc < nch; ++cc) {
        const int s0  = cc * Sc;
        const int Scc = (Sc < SS - s0) ? Sc : (SS - s0);

        // ======== gi phase: W_ih resident ========
#pragma unroll
        for (int t2 = 0; t2 < 6; ++t2) {
            const _Float16* base = Wih +
                (size_t)(((t2 >> 1) * 256 + w * 32 + (t2 & 1) * 16) + c) * HH + q * 8;
#pragma unroll
            for (int kt = 0; kt < 8; ++kt) wf[t2][kt] = *(const half8*)(base + kt * 32);
        }
        // pin into AGPRs: values must live in the acc half of the unified RF
#pragma unroll
        for (int t2 = 0; t2 < 6; ++t2)
#pragma unroll
            for (int kt = 0; kt < 8; ++kt)
                asm volatile("" : "+a"(wf[t2][kt]));

        fvec4 cf0 = __builtin_nontemporal_load((const fvec4*)(crow + (size_t)s0 * HH));
        fvec4 cf1 = __builtin_nontemporal_load((const fvec4*)(crow + (size_t)s0 * HH + 4));

        for (int sc = 0; sc < Scc; ++sc) {
            const int s = s0 + sc;
            {
                half8 hv;
                hv[0] = (_Float16)cf0.x; hv[1] = (_Float16)cf0.y;
                hv[2] = (_Float16)cf0.z; hv[3] = (_Float16)cf0.w;
                hv[4] = (_Float16)cf1.x; hv[5] = (_Float16)cf1.y;
                hv[6] = (_Float16)cf1.z; hv[7] = (_Float16)cf1.w;
                *(half8*)&cA[(sc & 1) * CABUF + m_st * APAD + chk * 8] = hv;
            }
            __syncthreads();
            if (sc + 1 < Scc) {
                cf0 = __builtin_nontemporal_load((const fvec4*)(crow + (size_t)(s + 1) * HH));
                cf1 = __builtin_nontemporal_load((const fvec4*)(crow + (size_t)(s + 1) * HH + 4));
            }
            floatx4 acc[6];
#pragma unroll
            for (int t2 = 0; t2 < 6; ++t2) acc[t2] = (floatx4){0.f, 0.f, 0.f, 0.f};
#pragma unroll
            for (int kt = 0; kt < 8; ++kt) {
                half8 a = *(const half8*)&cA[(sc & 1) * CABUF + c * APAD + kt * 32 + q * 8];
#pragma unroll
                for (int t2 = 0; t2 < 6; ++t2)
                    acc[t2] = __builtin_amdgcn_mfma_f32_16x16x32_f16(a, wf[t2][kt], acc[t2], 0, 0, 0);
            }
            // gi (+biases) -> LDS, thread-matched layout: 24 halfs = 48 B per thread
            half8 o[3];
#pragma unroll
            for (int t2 = 0; t2 < 6; ++t2)
#pragma unroll
                for (int r = 0; r < 4; ++r) {
                    int idx = t2 * 4 + r;
                    o[idx >> 3][idx & 7] = (_Float16)(acc[t2][r] + bsum[t2]);
                }
            _Float16* gp = giL + (size_t)sc * 12288 + tid * 24;
            *(half8*)gp        = o[0];
            *(half8*)(gp + 8)  = o[1];
            *(half8*)(gp + 16) = o[2];
        }

        // ======== scan phase: W_hh resident ========
#pragma unroll
        for (int t2 = 0; t2 < 6; ++t2) {
            const _Float16* base = Whh +
                (size_t)(((t2 >> 1) * 256 + w * 32 + (t2 & 1) * 16) + c) * HH + q * 8;
#pragma unroll
            for (int kt = 0; kt < 8; ++kt) wf[t2][kt] = *(const half8*)(base + kt * 32);
        }
#pragma unroll
        for (int t2 = 0; t2 < 6; ++t2)
#pragma unroll
            for (int kt = 0; kt < 8; ++kt)
                asm volatile("" : "+a"(wf[t2][kt]));

        for (int sc = 0; sc < Scc; ++sc) {
            const int s = s0 + sc;
            __syncthreads();   // hA[hp] ready

            floatx4 acch[6];
#pragma unroll
            for (int t2 = 0; t2 < 6; ++t2) acch[t2] = (floatx4){0.f, 0.f, 0.f, 0.f};
#pragma unroll
            for (int kt = 0; kt < 8; ++kt) {
                half8 a = *(const half8*)&hAb[hp * CABUF + c * APAD + kt * 32 + q * 8];
#pragma unroll
                for (int t2 = 0; t2 < 6; ++t2)
                    acch[t2] = __builtin_amdgcn_mfma_f32_16x16x32_f16(a, wf[t2][kt], acch[t2], 0, 0, 0);
            }

            // gi read-back AFTER the MFMA loop (own-thread LDS data, no barrier
            // needed) -> keeps peak arch-VGPR pressure during MFMAs low
            const _Float16* gp = giL + (size_t)sc * 12288 + tid * 24;
            half8 g0 = *(const half8*)gp;
            half8 g1 = *(const half8*)(gp + 8);
            half8 g2 = *(const half8*)(gp + 16);
            float gv[4];
#pragma unroll
            for (int r = 0; r < 4; ++r) gv[r] = gL[s * 16 + q * 4 + r];

            _Float16* hw = hAb + (hp ^ 1) * CABUF;
#pragma unroll
            for (int t = 0; t < 2; ++t)
#pragma unroll
                for (int r = 0; r < 4; ++r) {
                    float i_r = (float)g0[t * 4 + r];
                    float i_z = (float)g1[t * 4 + r];
                    float i_n = (float)g2[t * 4 + r];
                    float h_r = acch[0 * 2 + t][r];
                    float h_z = acch[1 * 2 + t][r];
                    float h_n = acch[2 * 2 + t][r] + bhn[t];
                    float rg = sigm(i_r + h_r);
                    float zg = sigm(i_z + h_z);
                    float ng = tanh_f(i_n + rg * h_n);
                    float hold = hreg[t][r];
                    float hnew = (1.f - zg) * ng + zg * hold;
                    float gg = gv[r];
                    float hout = gg * hnew + (1.f - gg) * hold;
                    hreg[t][r] = hout;
                    hw[(q * 4 + r) * APAD + w * 32 + t * 16 + c] = (_Float16)hout;
                }
            hp ^= 1;
        }
    }

#pragma unroll
    for (int t = 0; t < 2; ++t)
#pragma unroll
        for (int r = 0; r < 4; ++r)
            out[(size_t)(rb + q * 4 + r) * HH + w * 32 + t * 16 + c] = hreg[t][r];
}

extern "C" void kernel_launch(void* const* d_in, const int* in_sizes, int n_in,
                              void* d_out, int out_size, void* d_ws, size_t ws_size,
                              hipStream_t stream) {
    const float* C   = (const float*)d_in[0];
    const float* G   = (const float*)d_in[1];
    const float* Wih = (const float*)d_in[2];
    const float* Whh = (const float*)d_in[3];
    const float* bih = (const float*)d_in[4];
    const float* bhh = (const float*)d_in[5];
    _Float16* wsh = (_Float16*)d_ws;            // f16 weights: 786432 bytes

    // One-time: raise dynamic LDS limit for the Sc=5 config (159,872 B).
    // gfx950 supports 160 KiB/workgroup. Fallback Sc=1 (61,568 B) if refused.
    static int Sc_cached = 0;
    if (Sc_cached == 0) {
        const int shm5 = 5 * 24576 + 4 * CABUF * 2 + 16 * SS * 4;   // 159872
        hipError_t e = hipFuncSetAttribute((const void*)gru_all,
                          hipFuncAttributeMaxDynamicSharedMemorySize, shm5);
        Sc_cached = (e == hipSuccess) ? 5 : 1;
    }
    const int Sc = Sc_cached;
    const size_t shmem = (size_t)Sc * 24576 + 4 * CABUF * 2 + 16 * SS * 4;

    cvt_w<<<384, 256, 0, stream>>>(Wih, Whh, wsh);
    gru_all<<<256, 512, shmem, stream>>>(C, G, bih, bhh, wsh, (float*)d_out, Sc);
}

// Round 4
// 780.260 us; speedup vs baseline: 1.1027x; 1.1027x over previous
//
#include <hip/hip_runtime.h>
#include <hip/hip_fp16.h>

typedef _Float16 half8 __attribute__((ext_vector_type(8)));
typedef _Float16 half4 __attribute__((ext_vector_type(4)));
typedef float floatx4 __attribute__((ext_vector_type(4)));
typedef float fvec4 __attribute__((ext_vector_type(4)));

#define SS 50
#define HH 256
#define APAD 264                 // LDS row stride in halfs (528 B)
#define CABUF (16 * APAD)        // 4224 halfs per staging buffer
#define WHALF (768 * 256)        // halfs per weight matrix

__device__ __forceinline__ float sigm(float x) { return 1.f / (1.f + __expf(-x)); }
__device__ __forceinline__ float tanh_f(float x) {
    float ap = fabsf(x);
    float e2 = __expf(-2.f * ap);
    float th = (1.f - e2) / (1.f + e2);
    return (x < 0.f) ? -th : th;
}

// ---- phase 0: convert W_ih / W_hh fp32 -> fp16 into workspace ----
__global__ void cvt_w(const float* __restrict__ wih,
                      const float* __restrict__ whh,
                      _Float16* __restrict__ ws) {
    int idx = (blockIdx.x * 256 + threadIdx.x) * 4;
    const float* src = (idx < WHALF) ? (wih + idx) : (whh + (idx - WHALF));
    fvec4 v = *(const fvec4*)src;
    half4 h;
    h[0] = (_Float16)v.x; h[1] = (_Float16)v.y;
    h[2] = (_Float16)v.z; h[3] = (_Float16)v.w;
    *(half4*)(ws + idx) = h;
}

// ---- persistent fused kernel ----
// Dynamic LDS layout (halfs):
//   giL : Sc * 12288          (gi staging, thread-matched: tid*24)
//   cA  : 2 * CABUF           (C staging double buffer)
//   hA  : 2 * CABUF           (h f16 round-trip double buffer)
//   gL  : 16*SS floats        (G staged once per block, layout [s][row])
extern __shared__ _Float16 smem[];

// Register strategy, round 4: the allocator's arch-VGPR cap stayed at 128
// through launch_bounds(512,2) and waves_per_eu(2,2), forcing the 192-reg
// weight fragment set to spill to scratch (WRITE_SIZE 165-316 MB of spill
// traffic, ~14k cyc/step). amdgpu_num_vgpr(256) sets the allocation
// directly: 2 waves/SIMD x 256 regs = the full per-SIMD pool, and demand
// (192 weights + ~60 working set) fits with no spill.
__global__ __launch_bounds__(512)
__attribute__((amdgpu_waves_per_eu(2, 2)))
__attribute__((amdgpu_num_vgpr(256)))
void gru_all(
    const float* __restrict__ C, const float* __restrict__ G,
    const float* __restrict__ bih, const float* __restrict__ bhh,
    const _Float16* __restrict__ Wf, float* __restrict__ out, int Sc)
{
    _Float16* giL = smem;
    _Float16* cA  = smem + (size_t)Sc * 12288;
    _Float16* hAb = cA + 2 * CABUF;
    float*    gL  = (float*)(hAb + 2 * CABUF);

    const int tid  = threadIdx.x;
    const int w    = tid >> 6;
    const int lane = tid & 63;
    const int q    = lane >> 4;
    const int c    = lane & 15;
    const int rb   = blockIdx.x * 16;

    const _Float16* Wih = Wf;
    const _Float16* Whh = Wf + WHALF;

    // biases: bi (+ bh for r,z gates) folded into gi at store time; bh_n separate
    float bsum[6], bhn[2];
#pragma unroll
    for (int t2 = 0; t2 < 6; ++t2) {
        int g = t2 >> 1, t = t2 & 1;
        int n = g * 256 + w * 32 + t * 16 + c;
        bsum[t2] = bih[n] + (g < 2 ? bhh[n] : 0.f);
    }
#pragma unroll
    for (int t = 0; t < 2; ++t) bhn[t] = bhh[512 + w * 32 + t * 16 + c];

    float hreg[2][4];
#pragma unroll
    for (int t = 0; t < 2; ++t)
#pragma unroll
        for (int r = 0; r < 4; ++r) hreg[t][r] = 0.f;

    // init: zero h buffer 0, stage all G for this block's 16 rows
    for (int i = tid; i < CABUF; i += 512) hAb[i] = (_Float16)0.f;
    for (int i = tid; i < 16 * SS; i += 512)
        gL[i] = G[(size_t)(rb + (i & 15)) * SS + (i >> 4)];

    const int m_st = tid & 15;
    const int chk  = tid >> 4;             // 0..31, 8 floats each
    const float* crow = C + (size_t)(rb + m_st) * (SS * HH) + chk * 8;

    half8 wf[6][8];                        // 192 regs of weight fragments (resident)
    int hp = 0;
    const int nch = (SS + Sc - 1) / Sc;

    for (int cc = 0; cc < nch; ++cc) {
        const int s0  = cc * Sc;
        const int Scc = (Sc < SS - s0) ? Sc : (SS - s0);

        // ======== gi phase: W_ih resident ========
#pragma unroll
        for (int t2 = 0; t2 < 6; ++t2) {
            const _Float16* base = Wih +
                (size_t)(((t2 >> 1) * 256 + w * 32 + (t2 & 1) * 16) + c) * HH + q * 8;
#pragma unroll
            for (int kt = 0; kt < 8; ++kt) wf[t2][kt] = *(const half8*)(base + kt * 32);
        }
        // pin: values become opaque (non-rematerializable), so the loads
        // cannot be re-sunk into the MFMA loop
#pragma unroll
        for (int t2 = 0; t2 < 6; ++t2)
#pragma unroll
            for (int kt = 0; kt < 8; ++kt)
                asm volatile("" : "+v"(wf[t2][kt]));

        fvec4 cf0 = __builtin_nontemporal_load((const fvec4*)(crow + (size_t)s0 * HH));
        fvec4 cf1 = __builtin_nontemporal_load((const fvec4*)(crow + (size_t)s0 * HH + 4));

        for (int sc = 0; sc < Scc; ++sc) {
            const int s = s0 + sc;
            {
                half8 hv;
                hv[0] = (_Float16)cf0.x; hv[1] = (_Float16)cf0.y;
                hv[2] = (_Float16)cf0.z; hv[3] = (_Float16)cf0.w;
                hv[4] = (_Float16)cf1.x; hv[5] = (_Float16)cf1.y;
                hv[6] = (_Float16)cf1.z; hv[7] = (_Float16)cf1.w;
                *(half8*)&cA[(sc & 1) * CABUF + m_st * APAD + chk * 8] = hv;
            }
            __syncthreads();
            if (sc + 1 < Scc) {
                cf0 = __builtin_nontemporal_load((const fvec4*)(crow + (size_t)(s + 1) * HH));
                cf1 = __builtin_nontemporal_load((const fvec4*)(crow + (size_t)(s + 1) * HH + 4));
            }
            floatx4 acc[6];
#pragma unroll
            for (int t2 = 0; t2 < 6; ++t2) acc[t2] = (floatx4){0.f, 0.f, 0.f, 0.f};
#pragma unroll
            for (int kt = 0; kt < 8; ++kt) {
                half8 a = *(const half8*)&cA[(sc & 1) * CABUF + c * APAD + kt * 32 + q * 8];
#pragma unroll
                for (int t2 = 0; t2 < 6; ++t2)
                    acc[t2] = __builtin_amdgcn_mfma_f32_16x16x32_f16(a, wf[t2][kt], acc[t2], 0, 0, 0);
            }
            // gi (+biases) -> LDS, thread-matched layout: 24 halfs = 48 B per thread
            half8 o[3];
#pragma unroll
            for (int t2 = 0; t2 < 6; ++t2)
#pragma unroll
                for (int r = 0; r < 4; ++r) {
                    int idx = t2 * 4 + r;
                    o[idx >> 3][idx & 7] = (_Float16)(acc[t2][r] + bsum[t2]);
                }
            _Float16* gp = giL + (size_t)sc * 12288 + tid * 24;
            *(half8*)gp        = o[0];
            *(half8*)(gp + 8)  = o[1];
            *(half8*)(gp + 16) = o[2];
        }

        // ======== scan phase: W_hh resident ========
#pragma unroll
        for (int t2 = 0; t2 < 6; ++t2) {
            const _Float16* base = Whh +
                (size_t)(((t2 >> 1) * 256 + w * 32 + (t2 & 1) * 16) + c) * HH + q * 8;
#pragma unroll
            for (int kt = 0; kt < 8; ++kt) wf[t2][kt] = *(const half8*)(base + kt * 32);
        }
#pragma unroll
        for (int t2 = 0; t2 < 6; ++t2)
#pragma unroll
            for (int kt = 0; kt < 8; ++kt)
                asm volatile("" : "+v"(wf[t2][kt]));

        for (int sc = 0; sc < Scc; ++sc) {
            const int s = s0 + sc;
            __syncthreads();   // hA[hp] ready

            floatx4 acch[6];
#pragma unroll
            for (int t2 = 0; t2 < 6; ++t2) acch[t2] = (floatx4){0.f, 0.f, 0.f, 0.f};
#pragma unroll
            for (int kt = 0; kt < 8; ++kt) {
                half8 a = *(const half8*)&hAb[hp * CABUF + c * APAD + kt * 32 + q * 8];
#pragma unroll
                for (int t2 = 0; t2 < 6; ++t2)
                    acch[t2] = __builtin_amdgcn_mfma_f32_16x16x32_f16(a, wf[t2][kt], acch[t2], 0, 0, 0);
            }

            // gi read-back AFTER the MFMA loop (own-thread LDS data, no barrier
            // needed) -> keeps peak arch-VGPR pressure during MFMAs low
            const _Float16* gp = giL + (size_t)sc * 12288 + tid * 24;
            half8 g0 = *(const half8*)gp;
            half8 g1 = *(const half8*)(gp + 8);
            half8 g2 = *(const half8*)(gp + 16);
            float gv[4];
#pragma unroll
            for (int r = 0; r < 4; ++r) gv[r] = gL[s * 16 + q * 4 + r];

            _Float16* hw = hAb + (hp ^ 1) * CABUF;
#pragma unroll
            for (int t = 0; t < 2; ++t)
#pragma unroll
                for (int r = 0; r < 4; ++r) {
                    float i_r = (float)g0[t * 4 + r];
                    float i_z = (float)g1[t * 4 + r];
                    float i_n = (float)g2[t * 4 + r];
                    float h_r = acch[0 * 2 + t][r];
                    float h_z = acch[1 * 2 + t][r];
                    float h_n = acch[2 * 2 + t][r] + bhn[t];
                    float rg = sigm(i_r + h_r);
                    float zg = sigm(i_z + h_z);
                    float ng = tanh_f(i_n + rg * h_n);
                    float hold = hreg[t][r];
                    float hnew = (1.f - zg) * ng + zg * hold;
                    float gg = gv[r];
                    float hout = gg * hnew + (1.f - gg) * hold;
                    hreg[t][r] = hout;
                    hw[(q * 4 + r) * APAD + w * 32 + t * 16 + c] = (_Float16)hout;
                }
            hp ^= 1;
        }
    }

#pragma unroll
    for (int t = 0; t < 2; ++t)
#pragma unroll
        for (int r = 0; r < 4; ++r)
            out[(size_t)(rb + q * 4 + r) * HH + w * 32 + t * 16 + c] = hreg[t][r];
}

extern "C" void kernel_launch(void* const* d_in, const int* in_sizes, int n_in,
                              void* d_out, int out_size, void* d_ws, size_t ws_size,
                              hipStream_t stream) {
    const float* C   = (const float*)d_in[0];
    const float* G   = (const float*)d_in[1];
    const float* Wih = (const float*)d_in[2];
    const float* Whh = (const float*)d_in[3];
    const float* bih = (const float*)d_in[4];
    const float* bhh = (const float*)d_in[5];
    _Float16* wsh = (_Float16*)d_ws;            // f16 weights: 786432 bytes

    // One-time: raise dynamic LDS limit for the Sc=5 config (159,872 B).
    // gfx950 supports 160 KiB/workgroup. Fallback Sc=1 (61,568 B) if refused.
    static int Sc_cached = 0;
    if (Sc_cached == 0) {
        const int shm5 = 5 * 24576 + 4 * CABUF * 2 + 16 * SS * 4;   // 159872
        hipError_t e = hipFuncSetAttribute((const void*)gru_all,
                          hipFuncAttributeMaxDynamicSharedMemorySize, shm5);
        Sc_cached = (e == hipSuccess) ? 5 : 1;
    }
    const int Sc = Sc_cached;
    const size_t shmem = (size_t)Sc * 24576 + 4 * CABUF * 2 + 16 * SS * 4;

    cvt_w<<<384, 256, 0, stream>>>(Wih, Whh, wsh);
    gru_all<<<256, 512, shmem, stream>>>(C, G, bih, bhh, wsh, (float*)d_out, Sc);
}

// Round 5
// 742.762 us; speedup vs baseline: 1.1583x; 1.0505x over previous
//
#include <hip/hip_runtime.h>
#include <hip/hip_fp16.h>

typedef _Float16 half8 __attribute__((ext_vector_type(8)));
typedef _Float16 half4 __attribute__((ext_vector_type(4)));
typedef float floatx4 __attribute__((ext_vector_type(4)));
typedef float fvec4 __attribute__((ext_vector_type(4)));

#define SS 50
#define HH 256
#define APAD 264                 // LDS row stride in halfs (528 B)
#define CABUF (16 * APAD)        // 4224 halfs per staging buffer
#define WHALF (768 * 256)        // halfs per weight matrix

__device__ __forceinline__ float sigm(float x) { return 1.f / (1.f + __expf(-x)); }
__device__ __forceinline__ float tanh_f(float x) {
    float ap = fabsf(x);
    float e2 = __expf(-2.f * ap);
    float th = (1.f - e2) / (1.f + e2);
    return (x < 0.f) ? -th : th;
}

// ---- phase 0: convert W_ih / W_hh fp32 -> fp16 into workspace ----
__global__ void cvt_w(const float* __restrict__ wih,
                      const float* __restrict__ whh,
                      _Float16* __restrict__ ws) {
    int idx = (blockIdx.x * 256 + threadIdx.x) * 4;
    const float* src = (idx < WHALF) ? (wih + idx) : (whh + (idx - WHALF));
    fvec4 v = *(const fvec4*)src;
    half4 h;
    h[0] = (_Float16)v.x; h[1] = (_Float16)v.y;
    h[2] = (_Float16)v.z; h[3] = (_Float16)v.w;
    *(half4*)(ws + idx) = h;
}

// ---- persistent fused kernel, round 5 geometry ----
// R1-R4 evidence: allocator arch-VGPR cap is immovably 128 (three attribute
// mechanisms tried), so the old 8-wave layout (6 weight tiles = 192 regs per
// wave) guaranteed a scratch-spill storm (WRITE_SIZE 165-316 MB, ~14k
// cyc/step). Fix by GEOMETRY: 16 waves (1024 thr), each wave owns 16 cols
// per gate -> 3 tiles -> 96 weight regs, which FITS the 128 cap. A
// 1024-thread workgroup also forces the backend to <=128 VGPRs (16 waves
// co-resident), making the cap correct instead of catastrophic.
//
// Dynamic LDS layout (halfs):
//   giL : Sc * 12288          (gi staging, thread-matched: tid*12 halfs)
//   cA  : 2 * CABUF           (C staging double buffer)
//   hA  : 2 * CABUF           (h f16 round-trip double buffer)
//   gL  : 16*SS floats        (G staged once per block, layout [s][row])
extern __shared__ _Float16 smem[];

__global__ __launch_bounds__(1024)
__attribute__((amdgpu_waves_per_eu(4, 4)))
void gru_all(
    const float* __restrict__ C, const float* __restrict__ G,
    const float* __restrict__ bih, const float* __restrict__ bhh,
    const _Float16* __restrict__ Wf, float* __restrict__ out, int Sc)
{
    _Float16* giL = smem;
    _Float16* cA  = smem + (size_t)Sc * 12288;
    _Float16* hAb = cA + 2 * CABUF;
    float*    gL  = (float*)(hAb + 2 * CABUF);

    const int tid  = threadIdx.x;
    const int w    = tid >> 6;          // 0..15, wave owns cols [16w,16w+16) per gate
    const int lane = tid & 63;
    const int q    = lane >> 4;
    const int c    = lane & 15;
    const int rb   = blockIdx.x * 16;

    const _Float16* Wih = Wf;
    const _Float16* Whh = Wf + WHALF;

    // biases: bi (+ bh for r,z gates) folded into gi at store time; bh_n separate
    float bsum[3], bhn;
#pragma unroll
    for (int g = 0; g < 3; ++g) {
        int n = g * 256 + w * 16 + c;
        bsum[g] = bih[n] + (g < 2 ? bhh[n] : 0.f);
    }
    bhn = bhh[512 + w * 16 + c];

    float hreg[4];
#pragma unroll
    for (int r = 0; r < 4; ++r) hreg[r] = 0.f;

    // init: zero h buffer 0, stage all G for this block's 16 rows
    for (int i = tid; i < CABUF; i += 1024) hAb[i] = (_Float16)0.f;
    for (int i = tid; i < 16 * SS; i += 1024)
        gL[i] = G[(size_t)(rb + (i & 15)) * SS + (i >> 4)];

    const int m_st = tid & 15;
    const int chk  = tid >> 4;             // 0..63, 4 floats each
    const float* crow = C + (size_t)(rb + m_st) * (SS * HH) + chk * 4;

    half8 wf[3][8];                        // 96 regs of weight fragments (resident)
    int hp = 0;
    const int nch = (SS + Sc - 1) / Sc;

    for (int cc = 0; cc < nch; ++cc) {
        const int s0  = cc * Sc;
        const int Scc = (Sc < SS - s0) ? Sc : (SS - s0);

        // ======== gi phase: W_ih resident ========
#pragma unroll
        for (int g = 0; g < 3; ++g) {
            const _Float16* base = Wih +
                (size_t)(g * 256 + w * 16 + c) * HH + q * 8;
#pragma unroll
            for (int kt = 0; kt < 8; ++kt) wf[g][kt] = *(const half8*)(base + kt * 32);
        }
#pragma unroll
        for (int g = 0; g < 3; ++g)
#pragma unroll
            for (int kt = 0; kt < 8; ++kt)
                asm volatile("" : "+v"(wf[g][kt]));

        fvec4 cf = __builtin_nontemporal_load((const fvec4*)(crow + (size_t)s0 * HH));

        for (int sc = 0; sc < Scc; ++sc) {
            const int s = s0 + sc;
            {
                half4 hv;
                hv[0] = (_Float16)cf.x; hv[1] = (_Float16)cf.y;
                hv[2] = (_Float16)cf.z; hv[3] = (_Float16)cf.w;
                *(half4*)&cA[(sc & 1) * CABUF + m_st * APAD + chk * 4] = hv;
            }
            __syncthreads();
            if (sc + 1 < Scc)
                cf = __builtin_nontemporal_load((const fvec4*)(crow + (size_t)(s + 1) * HH));

            floatx4 acc[3];
#pragma unroll
            for (int g = 0; g < 3; ++g) acc[g] = (floatx4){0.f, 0.f, 0.f, 0.f};
#pragma unroll
            for (int kt = 0; kt < 8; ++kt) {
                half8 a = *(const half8*)&cA[(sc & 1) * CABUF + c * APAD + kt * 32 + q * 8];
#pragma unroll
                for (int g = 0; g < 3; ++g)
                    acc[g] = __builtin_amdgcn_mfma_f32_16x16x32_f16(a, wf[g][kt], acc[g], 0, 0, 0);
            }
            // gi (+biases) -> LDS, thread-matched: 12 halfs = 24 B per thread
            _Float16* gp = giL + (size_t)sc * 12288 + tid * 12;
#pragma unroll
            for (int g = 0; g < 3; ++g) {
                half4 o;
#pragma unroll
                for (int r = 0; r < 4; ++r) o[r] = (_Float16)(acc[g][r] + bsum[g]);
                *(half4*)(gp + g * 4) = o;
            }
        }

        // ======== scan phase: W_hh resident ========
#pragma unroll
        for (int g = 0; g < 3; ++g) {
            const _Float16* base = Whh +
                (size_t)(g * 256 + w * 16 + c) * HH + q * 8;
#pragma unroll
            for (int kt = 0; kt < 8; ++kt) wf[g][kt] = *(const half8*)(base + kt * 32);
        }
#pragma unroll
        for (int g = 0; g < 3; ++g)
#pragma unroll
            for (int kt = 0; kt < 8; ++kt)
                asm volatile("" : "+v"(wf[g][kt]));

        for (int sc = 0; sc < Scc; ++sc) {
            const int s = s0 + sc;
            __syncthreads();   // hA[hp] ready

            floatx4 acch[3];
#pragma unroll
            for (int g = 0; g < 3; ++g) acch[g] = (floatx4){0.f, 0.f, 0.f, 0.f};
#pragma unroll
            for (int kt = 0; kt < 8; ++kt) {
                half8 a = *(const half8*)&hAb[hp * CABUF + c * APAD + kt * 32 + q * 8];
#pragma unroll
                for (int g = 0; g < 3; ++g)
                    acch[g] = __builtin_amdgcn_mfma_f32_16x16x32_f16(a, wf[g][kt], acch[g], 0, 0, 0);
            }

            // gi read-back AFTER the MFMA loop (own-thread LDS data, short-lived)
            const _Float16* gp = giL + (size_t)sc * 12288 + tid * 12;
            half4 g0 = *(const half4*)gp;
            half4 g1 = *(const half4*)(gp + 4);
            half4 g2 = *(const half4*)(gp + 8);

            _Float16* hw = hAb + (hp ^ 1) * CABUF;
#pragma unroll
            for (int r = 0; r < 4; ++r) {
                float i_r = (float)g0[r];
                float i_z = (float)g1[r];
                float i_n = (float)g2[r];
                float h_r = acch[0][r];
                float h_z = acch[1][r];
                float h_n = acch[2][r] + bhn;
                float rg = sigm(i_r + h_r);
                float zg = sigm(i_z + h_z);
                float ng = tanh_f(i_n + rg * h_n);
                float hold = hreg[r];
                float hnew = (1.f - zg) * ng + zg * hold;
                float gg = gL[s * 16 + q * 4 + r];
                float hout = gg * hnew + (1.f - gg) * hold;
                hreg[r] = hout;
                hw[(q * 4 + r) * APAD + w * 16 + c] = (_Float16)hout;
            }
            hp ^= 1;
        }
    }

#pragma unroll
    for (int r = 0; r < 4; ++r)
        out[(size_t)(rb + q * 4 + r) * HH + w * 16 + c] = hreg[r];
}

extern "C" void kernel_launch(void* const* d_in, const int* in_sizes, int n_in,
                              void* d_out, int out_size, void* d_ws, size_t ws_size,
                              hipStream_t stream) {
    const float* C   = (const float*)d_in[0];
    const float* G   = (const float*)d_in[1];
    const float* Wih = (const float*)d_in[2];
    const float* Whh = (const float*)d_in[3];
    const float* bih = (const float*)d_in[4];
    const float* bhh = (const float*)d_in[5];
    _Float16* wsh = (_Float16*)d_ws;            // f16 weights: 786432 bytes

    // One-time: raise dynamic LDS limit for the Sc=5 config (159,872 B).
    // gfx950 supports 160 KiB/workgroup. Fallback Sc=1 (61,568 B) if refused.
    static int Sc_cached = 0;
    if (Sc_cached == 0) {
        const int shm5 = 5 * 24576 + 4 * CABUF * 2 + 16 * SS * 4;   // 159872
        hipError_t e = hipFuncSetAttribute((const void*)gru_all,
                          hipFuncAttributeMaxDynamicSharedMemorySize, shm5);
        Sc_cached = (e == hipSuccess) ? 5 : 1;
    }
    const int Sc = Sc_cached;
    const size_t shmem = (size_t)Sc * 24576 + 4 * CABUF * 2 + 16 * SS * 4;

    cvt_w<<<384, 256, 0, stream>>>(Wih, Whh, wsh);
    gru_all<<<256, 1024, shmem, stream>>>(C, G, bih, bhh, wsh, (float*)d_out, Sc);
}